// Round 14
// baseline (435.540 us; speedup 1.0000x reference)
//
#include <hip/hip_runtime.h>
#include <hip/hip_bf16.h>
#include <math.h>

#define DIM 512
#define HID 2048
#define NE  8
#define CSTRIDE 32   // counter padding: 128B apart
#define CVTB 1024    // blocks of k_init doing weight conversion

typedef __attribute__((ext_vector_type(8))) short short8;
typedef __attribute__((ext_vector_type(4))) float f32x4;
typedef unsigned short ushort_t;

static __device__ __forceinline__ ushort_t f2bf(float f) {
    unsigned int x = __builtin_bit_cast(unsigned int, f);
    unsigned int lsb = (x >> 16) & 1u;
    x += 0x7fffu + lsb;
    return (ushort_t)(x >> 16);
}

// tanh-form gelu in sigmoid form: ~8 VALU ops, no LDS (r10's LUT caused 7.8M
// bank conflicts). |err vs erf-gelu| <= ~1e-3 in h -> ~3e-4 in y, << 2e-2.
static __device__ __forceinline__ float fast_gelu(float v) {
    float z = v * fmaf(0.071354816f, v * v, 1.5957691f);
    return v * __builtin_amdgcn_rcpf(1.f + __expf(-z));
}

// async global->LDS, 16B per lane. LDS dest must be the WAVE-UNIFORM base.
static __device__ __forceinline__ void gld16(const void* g, void* l) {
    __builtin_amdgcn_global_load_lds(
        (const __attribute__((address_space(1))) void*)g,
        (__attribute__((address_space(3))) void*)l,
        16, 0, 0);
}

// ---------------- fused init: weight cvt (blocks 0..CVTB) + router (rest) ----------------
__global__ __launch_bounds__(256) void k_init(
    const float* __restrict__ W1, ushort_t* __restrict__ W1b, int n1,
    const float* __restrict__ W2, ushort_t* __restrict__ W2b, int n2,
    const float* __restrict__ x, const float* __restrict__ Wr,
    ushort_t* __restrict__ xb, float* __restrict__ probs,
    int* __restrict__ tidx, float* __restrict__ tw, int T)
{
    if (blockIdx.x < CVTB) {
        int i = blockIdx.x * 256 + threadIdx.x;
        int stride = CVTB * 256;
        int n4a = n1 >> 2, n4b = n2 >> 2;
        for (int j = i; j < n4a; j += stride) {
            float4 v = ((const float4*)W1)[j];
            ushort4 o;
            o.x = f2bf(v.x); o.y = f2bf(v.y); o.z = f2bf(v.z); o.w = f2bf(v.w);
            ((ushort4*)W1b)[j] = o;
        }
        for (int j = i; j < n4b; j += stride) {
            float4 v = ((const float4*)W2)[j];
            ushort4 o;
            o.x = f2bf(v.x); o.y = f2bf(v.y); o.z = f2bf(v.z); o.w = f2bf(v.w);
            ((ushort4*)W2b)[j] = o;
        }
        return;
    }
    int lane = threadIdx.x & 63;
    int t = (blockIdx.x - CVTB) * 4 + (threadIdx.x >> 6);
    if (t >= T) return;
    const float* xr = x + (size_t)t * DIM;
    double acc[NE];
#pragma unroll
    for (int e = 0; e < NE; e++) acc[e] = 0.0;
    for (int i = lane; i < DIM; i += 64) {
        float xv = xr[i];
        xb[(size_t)t * DIM + i] = f2bf(xv);
        double xd = (double)xv;
#pragma unroll
        for (int e = 0; e < NE; e++) acc[e] += xd * (double)Wr[e * DIM + i];
    }
#pragma unroll
    for (int e = 0; e < NE; e++) {
#pragma unroll
        for (int off = 32; off > 0; off >>= 1) acc[e] += __shfl_xor(acc[e], off);
    }
    double mx = acc[0];
#pragma unroll
    for (int e = 1; e < NE; e++) mx = fmax(mx, acc[e]);
    double p[NE], sum = 0.0;
#pragma unroll
    for (int e = 0; e < NE; e++) { p[e] = exp(acc[e] - mx); sum += p[e]; }
    float pr[NE];
#pragma unroll
    for (int e = 0; e < NE; e++) pr[e] = (float)(p[e] / sum);
    if (lane < NE) probs[(size_t)t * NE + lane] = pr[lane];
    if (lane == 0) {
        int i1 = 0; float b1v = pr[0];
#pragma unroll
        for (int e = 1; e < NE; e++) if (pr[e] > b1v) { b1v = pr[e]; i1 = e; }
        int i2 = -1; float b2v = -1.f;
#pragma unroll
        for (int e = 0; e < NE; e++) if (e != i1 && pr[e] > b2v) { b2v = pr[e]; i2 = e; }
        float s2 = b1v + b2v + 1e-8f;
        tidx[t * 2] = i1; tidx[t * 2 + 1] = i2;
        tw[t * 2] = b1v / s2; tw[t * 2 + 1] = b2v / s2;
    }
}

// ---------------- per-(slot,expert) histogram: block-aggregated ----------------
__global__ __launch_bounds__(256) void k_hist(const int* __restrict__ tidx,
                                              int* __restrict__ cnt, int T) {
    __shared__ int h[16];
    if (threadIdx.x < 16) h[threadIdx.x] = 0;
    __syncthreads();
    int stride = gridDim.x * blockDim.x;
    for (int t = blockIdx.x * blockDim.x + threadIdx.x; t < T; t += stride) {
        atomicAdd(&h[tidx[t * 2]], 1);
        atomicAdd(&h[8 + tidx[t * 2 + 1]], 1);
    }
    __syncthreads();
    if (threadIdx.x < 16 && h[threadIdx.x] != 0)
        atomicAdd(&cnt[threadIdx.x * CSTRIDE], h[threadIdx.x]);
}

// ---------------- fused: capacity keep + renorm + merged build + aux partials ----------------
__global__ __launch_bounds__(256) void k_post(const int* __restrict__ tidx,
        const float* __restrict__ tw, const int* __restrict__ cnt,
        const float* __restrict__ probs, int* __restrict__ lcnt,
        int* __restrict__ ltok, float* __restrict__ lwb,
        float* __restrict__ partial, int T, int cap, int capM)
{
    __shared__ int h[NE];
    __shared__ int base[NE];
    __shared__ float red[256 * 16];
    if (threadIdx.x < NE) h[threadIdx.x] = 0;
    __syncthreads();
    int t = blockIdx.x * blockDim.x + threadIdx.x;
    float wkn[2] = {0.f, 0.f};
    int myE[2] = {-1, -1};
    int myp[2] = {0, 0};
    if (t < T) {
        float wk[2]; int es[2];
#pragma unroll
        for (int s = 0; s < 2; s++) {
            int e = tidx[t * 2 + s];
            float w = tw[t * 2 + s];
            es[s] = e; wk[s] = w;
            if (cnt[(s * NE + e) * CSTRIDE] > cap) {   // rare: exact stable-sort rank
                int rank = 0;
                for (int t2 = 0; t2 < T; t2++) {
                    if (tidx[t2 * 2 + s] == e) {
                        float w2 = tw[t2 * 2 + s];
                        if (w2 > w || (w2 == w && t2 < t)) rank++;
                    }
                }
                if (rank >= cap) wk[s] = 0.f;
            }
        }
        float denom = fmaxf(wk[0] + wk[1], 1e-8f);
#pragma unroll
        for (int s = 0; s < 2; s++) {
            wkn[s] = wk[s] / denom;
            if (wkn[s] != 0.f) {
                myE[s] = es[s];
                myp[s] = atomicAdd(&h[es[s]], 1);   // LDS atomic
            }
        }
    }
    __syncthreads();
    if (threadIdx.x < NE)
        base[threadIdx.x] = (h[threadIdx.x] != 0)
            ? atomicAdd(&lcnt[threadIdx.x * CSTRIDE], h[threadIdx.x]) : 0;
    __syncthreads();
    float imp[NE], ld[NE];
#pragma unroll
    for (int e = 0; e < NE; e++) { imp[e] = 0.f; ld[e] = 0.f; }
    if (t < T) {
#pragma unroll
        for (int s = 0; s < 2; s++) {
            if (myE[s] >= 0) {
                int p = base[myE[s]] + myp[s];
                ltok[myE[s] * capM + p] = t;
                lwb[myE[s] * capM + p] = wkn[s];
                ld[myE[s]] += wkn[s];
            }
        }
#pragma unroll
        for (int e = 0; e < NE; e++) imp[e] = probs[(size_t)t * NE + e];
    }
#pragma unroll
    for (int e = 0; e < NE; e++) {
        red[threadIdx.x * 16 + e] = imp[e];
        red[threadIdx.x * 16 + 8 + e] = ld[e];
    }
    __syncthreads();
    for (int off = 128; off > 0; off >>= 1) {
        if (threadIdx.x < off) {
#pragma unroll
            for (int j = 0; j < 16; j++)
                red[threadIdx.x * 16 + j] += red[(threadIdx.x + off) * 16 + j];
        }
        __syncthreads();
    }
    if (threadIdx.x < 16) partial[blockIdx.x * 16 + threadIdx.x] = red[threadIdx.x];
}

// ---------------- tail: 128-aligned prefix offsets + aux final ----------------
__global__ void k_tail(const int* __restrict__ lcnt, int* __restrict__ loff,
                       const float* __restrict__ partial, float* __restrict__ outaux,
                       int nb, int T)
{
    __shared__ float s[16];
    if (threadIdx.x == 0) {
        int o = 0;
        for (int e = 0; e < NE; e++) {
            loff[e] = o;
            o += ((lcnt[e * CSTRIDE] + 127) >> 7) << 7;   // 128-row aligned tiles
        }
        loff[NE] = o;
    }
    if (threadIdx.x < 16) {
        float a = 0.f;
        for (int b = 0; b < nb; b++) a += partial[b * 16 + threadIdx.x];
        s[threadIdx.x] = a;
    }
    __syncthreads();
    if (threadIdx.x == 0) {
        float invT = 1.f / (float)T;
        float aux = 0.f;
        for (int e = 0; e < NE; e++)
            aux += (s[e] * invT) * (s[8 + e] * invT) * (float)NE;
        outaux[0] = aux;
    }
}

// ---------------- fc1: h = gelu(X @ W1^T + b1), 128x128, dbuf + counted vmcnt ----------------
// Pipeline (r9/r11-proven): STAGE(t+1) -> s_waitcnt vmcnt(8) -> raw s_barrier
// -> COMPUTE -> s_barrier. acc initialized with BIAS (C-in carries it through).
__global__ __launch_bounds__(256, 2) void k_fc1(
    const ushort_t* __restrict__ xb, const ushort_t* __restrict__ W1b,
    const float* __restrict__ b1, const int* __restrict__ lcnt,
    const int* __restrict__ loff, const int* __restrict__ ltok,
    ushort_t* __restrict__ hbuf, int capM)
{
    int bx = blockIdx.x;
    int e  = bx & 7;                 // expert == XCD residue
    int r  = bx >> 3;
    int mt = r >> 4;                 // HID/128 = 16 n-tiles, nt fastest
    int nt = r & 15;
    int cnt = lcnt[e * CSTRIDE];
    if (cnt > capM) cnt = capM;
    int m0 = mt * 128;
    if (m0 >= cnt) return;
    int n0 = nt * 128;
    const int* toks = ltok + e * capM;
    int hrow0 = loff[e] + m0;
    const ushort_t* Bsrc = W1b + (size_t)e * HID * DIM;

    __shared__ char smem[65536];     // dbuf: 2 x (16K A + 16K B)
    char* As0 = smem;          char* Bs0 = smem + 16384;
    char* As1 = smem + 32768;  char* Bs1 = smem + 49152;

    int tid = threadIdx.x;
    int wave = tid >> 6, lane = tid & 63;
    int wm = wave >> 1, wn = wave & 1;

    const char* aSrc[4]; const char* bSrc[4]; int ldst[4];
#pragma unroll
    for (int i = 0; i < 4; i++) {
        int c = tid + 256 * i;
        int row = c >> 3, cc = c & 7;
        int scc = cc ^ (row & 7);          // pre-swizzled source column chunk
        int gr = m0 + row;
        int tok = toks[gr < cnt ? gr : (cnt - 1)];
        aSrc[i] = (const char*)(xb + (size_t)tok * DIM + scc * 8);
        bSrc[i] = (const char*)(Bsrc + (size_t)(n0 + row) * DIM + scc * 8);
        ldst[i] = (i * 256 + wave * 64) * 16;
    }

    // acc init = bias (same per-column bias for every mf row-block)
    const float* b1e = b1 + e * HID;
    int nbase0 = n0 + wn * 64 + (lane >> 4) * 4;
    f32x4 acc[4][4];
#pragma unroll
    for (int nf = 0; nf < 4; nf++) {
        float4 bias4 = *(const float4*)(b1e + nbase0 + nf * 16);
        f32x4 bi = (f32x4){bias4.x, bias4.y, bias4.z, bias4.w};
#pragma unroll
        for (int mf = 0; mf < 4; mf++) acc[mf][nf] = bi;
    }

    int aRow = wm * 64 + (lane & 15);
    int bRow = wn * 64 + (lane & 15);
    int kq = lane >> 4;
    int swz0 = (kq ^ (lane & 7)) << 4;
    int swz1 = ((4 + kq) ^ (lane & 7)) << 4;
    int aoff[2] = { aRow * 128 + swz0, aRow * 128 + swz1 };
    int boff[2] = { bRow * 128 + swz0, bRow * 128 + swz1 };

    auto STAGE = [&](int kofs, char* A, char* B) {
#pragma unroll
        for (int i = 0; i < 4; i++) {
            gld16(aSrc[i] + kofs, A + ldst[i]);
            gld16(bSrc[i] + kofs, B + ldst[i]);
        }
    };
    auto COMPUTE = [&](const char* A, const char* B) {
#pragma unroll
        for (int kk = 0; kk < 2; kk++) {
            short8 af[4], bfr[4];
#pragma unroll
            for (int mf = 0; mf < 4; mf++)
                af[mf] = *(const short8*)(A + aoff[kk] + mf * 2048);
#pragma unroll
            for (int nf = 0; nf < 4; nf++)
                bfr[nf] = *(const short8*)(B + boff[kk] + nf * 2048);
#pragma unroll
            for (int mf = 0; mf < 4; mf++)
#pragma unroll
                for (int nf = 0; nf < 4; nf++)
                    acc[mf][nf] = __builtin_amdgcn_mfma_f32_16x16x32_bf16(bfr[nf], af[mf], acc[mf][nf], 0, 0, 0);
        }
    };

    const int NT = DIM / 64;   // 8
    STAGE(0, As0, Bs0);
#pragma unroll
    for (int t = 0; t < NT; t++) {
        char* Ac = (t & 1) ? As1 : As0;
        char* Bc = (t & 1) ? Bs1 : Bs0;
        if (t + 1 < NT) {
            STAGE((t + 1) * 128, (t & 1) ? As0 : As1, (t & 1) ? Bs0 : Bs1);
            asm volatile("s_waitcnt vmcnt(8)" ::: "memory");   // tile t done; t+1 in flight
        } else {
            asm volatile("s_waitcnt vmcnt(0)" ::: "memory");
        }
        __builtin_amdgcn_s_barrier();
        __builtin_amdgcn_sched_barrier(0);
        COMPUTE(Ac, Bc);
        __builtin_amdgcn_sched_barrier(0);
        __builtin_amdgcn_s_barrier();                          // buffer free for t+2
    }

    int mlocal = wm * 64 + (lane & 15);
#pragma unroll
    for (int mf = 0; mf < 4; mf++) {
        int mrow = mlocal + mf * 16;
        bool valid = (m0 + mrow) < cnt;
        ushort_t* dst = hbuf + (size_t)(hrow0 + mrow) * HID;
#pragma unroll
        for (int nf = 0; nf < 4; nf++) {
            int nc = nbase0 + nf * 16;
            ushort4 o;
            o.x = f2bf(fast_gelu(acc[mf][nf][0]));
            o.y = f2bf(fast_gelu(acc[mf][nf][1]));
            o.z = f2bf(fast_gelu(acc[mf][nf][2]));
            o.w = f2bf(fast_gelu(acc[mf][nf][3]));
            if (valid) *(ushort4*)(dst + nc) = o;
        }
    }
}

// ---------------- fc2: out[tok] += w * (H @ W2^T + b2), atomic f32 writeout ----------------
// Deterministic: each out element gets EXACTLY 2 contributions (token's experts
// distinct); fl(fl(0+a)+b) == fl(fl(0+b)+a) -> order-independent bitwise.
__global__ __launch_bounds__(256, 2) void k_fc2(
    const ushort_t* __restrict__ hbuf, const ushort_t* __restrict__ W2b,
    const float* __restrict__ b2, const int* __restrict__ lcnt,
    const int* __restrict__ loff, const int* __restrict__ ltok,
    const float* __restrict__ lwb, float* __restrict__ out, int capM)
{
    int bx = blockIdx.x;
    int e  = bx & 7;
    int r  = bx >> 3;
    int mt = r >> 2;                 // DIM/128 = 4 n-tiles
    int nt = r & 3;
    int cnt = lcnt[e * CSTRIDE];
    if (cnt > capM) cnt = capM;
    int m0 = mt * 128;
    if (m0 >= cnt) return;
    int n0 = nt * 128;
    int hrow0 = loff[e] + m0;
    const ushort_t* Bsrc = W2b + (size_t)e * DIM * HID;

    __shared__ char smem[65536];
    char* As0 = smem;          char* Bs0 = smem + 16384;
    char* As1 = smem + 32768;  char* Bs1 = smem + 49152;

    int tid = threadIdx.x;
    int wave = tid >> 6, lane = tid & 63;
    int wm = wave >> 1, wn = wave & 1;

    const char* aSrc[4]; const char* bSrc[4]; int ldst[4];
#pragma unroll
    for (int i = 0; i < 4; i++) {
        int c = tid + 256 * i;
        int row = c >> 3, cc = c & 7;
        int scc = cc ^ (row & 7);
        aSrc[i] = (const char*)(hbuf + (size_t)(hrow0 + row) * HID + scc * 8);
        bSrc[i] = (const char*)(Bsrc + (size_t)(n0 + row) * HID + scc * 8);
        ldst[i] = (i * 256 + wave * 64) * 16;
    }

    const float* b2e = b2 + e * DIM;
    int nbase0 = n0 + wn * 64 + (lane >> 4) * 4;
    f32x4 acc[4][4];
#pragma unroll
    for (int nf = 0; nf < 4; nf++) {
        float4 bias4 = *(const float4*)(b2e + nbase0 + nf * 16);
        f32x4 bi = (f32x4){bias4.x, bias4.y, bias4.z, bias4.w};
#pragma unroll
        for (int mf = 0; mf < 4; mf++) acc[mf][nf] = bi;
    }

    int aRow = wm * 64 + (lane & 15);
    int bRow = wn * 64 + (lane & 15);
    int kq = lane >> 4;
    int swz0 = (kq ^ (lane & 7)) << 4;
    int swz1 = ((4 + kq) ^ (lane & 7)) << 4;
    int aoff[2] = { aRow * 128 + swz0, aRow * 128 + swz1 };
    int boff[2] = { bRow * 128 + swz0, bRow * 128 + swz1 };

    auto STAGE = [&](int kofs, char* A, char* B) {
#pragma unroll
        for (int i = 0; i < 4; i++) {
            gld16(aSrc[i] + kofs, A + ldst[i]);
            gld16(bSrc[i] + kofs, B + ldst[i]);
        }
    };
    auto COMPUTE = [&](const char* A, const char* B) {
#pragma unroll
        for (int kk = 0; kk < 2; kk++) {
            short8 af[4], bfr[4];
#pragma unroll
            for (int mf = 0; mf < 4; mf++)
                af[mf] = *(const short8*)(A + aoff[kk] + mf * 2048);
#pragma unroll
            for (int nf = 0; nf < 4; nf++)
                bfr[nf] = *(const short8*)(B + boff[kk] + nf * 2048);
#pragma unroll
            for (int mf = 0; mf < 4; mf++)
#pragma unroll
                for (int nf = 0; nf < 4; nf++)
                    acc[mf][nf] = __builtin_amdgcn_mfma_f32_16x16x32_bf16(bfr[nf], af[mf], acc[mf][nf], 0, 0, 0);
        }
    };

    const int NT = HID / 64;   // 32 (byte offsets 0..3968 fit 13-bit signed imm)
    STAGE(0, As0, Bs0);
#pragma unroll
    for (int t = 0; t < NT; t++) {
        char* Ac = (t & 1) ? As1 : As0;
        char* Bc = (t & 1) ? Bs1 : Bs0;
        if (t + 1 < NT) {
            STAGE((t + 1) * 128, (t & 1) ? As0 : As1, (t & 1) ? Bs0 : Bs1);
            asm volatile("s_waitcnt vmcnt(8)" ::: "memory");
        } else {
            asm volatile("s_waitcnt vmcnt(0)" ::: "memory");
        }
        __builtin_amdgcn_s_barrier();
        __builtin_amdgcn_sched_barrier(0);
        COMPUTE(Ac, Bc);
        __builtin_amdgcn_sched_barrier(0);
        __builtin_amdgcn_s_barrier();
    }

    const int* toks = ltok + e * capM;
    const float* lws = lwb + e * capM;
    int mlocal = wm * 64 + (lane & 15);
#pragma unroll
    for (int mf = 0; mf < 4; mf++) {
        int gr = m0 + mlocal + mf * 16;
        if (gr < cnt) {
            int tok = toks[gr];
            float wgt = lws[gr];
            float* orow = out + (size_t)tok * DIM;
#pragma unroll
            for (int nf = 0; nf < 4; nf++) {
                int nc = nbase0 + nf * 16;
#pragma unroll
                for (int j = 0; j < 4; j++)
                    atomicAdd(&orow[nc + j], wgt * acc[mf][nf][j]);
            }
        }
    }
}

// ---------------- launch ----------------
extern "C" void kernel_launch(void* const* d_in, const int* in_sizes, int n_in,
                              void* d_out, int out_size, void* d_ws, size_t ws_size,
                              hipStream_t stream)
{
    const float* x  = (const float*)d_in[0];
    const float* Wr = (const float*)d_in[1];
    const float* W1 = (const float*)d_in[2];
    const float* b1 = (const float*)d_in[3];
    const float* W2 = (const float*)d_in[4];
    const float* b2 = (const float*)d_in[5];
    float* out = (float*)d_out;

    int T = in_sizes[0] / DIM;
    int cap = (int)(1.25 * (double)T * 2.0 / 8.0);
    if (cap < 1) cap = 1;
    int capM = 2 * cap; if (capM > T) capM = T;      // merged per-expert bound
    int mtmax = (capM + 127) / 128;                   // 128-row m-tiles
    int nposts = (T + 255) / 256;

    char* w = (char*)d_ws;
    size_t off = 0;
    auto alloc = [&](size_t bytes) {
        char* p = w + off;
        off = (off + bytes + 255) & ~(size_t)255;
        return p;
    };
    size_t hrows = (size_t)T * 2 + NE * 128;
    ushort_t* xb   = (ushort_t*)alloc((size_t)T * DIM * 2);
    ushort_t* W1b  = (ushort_t*)alloc((size_t)NE * HID * DIM * 2);
    ushort_t* W2b  = (ushort_t*)alloc((size_t)NE * DIM * HID * 2);
    ushort_t* hbuf = (ushort_t*)alloc(hrows * HID * 2);
    float* probs   = (float*)alloc((size_t)T * NE * 4);
    int*   tidx    = (int*)alloc((size_t)T * 2 * 4);
    float* tw      = (float*)alloc((size_t)T * 2 * 4);
    int*   cnt     = (int*)alloc(16 * CSTRIDE * 4);
    int*   lcnt    = (int*)alloc(NE * CSTRIDE * 4);
    int*   loff    = (int*)alloc((NE + 1) * 4);
    int*   ltok    = (int*)alloc((size_t)NE * capM * 4);
    float* lwb     = (float*)alloc((size_t)NE * capM * 4);
    float* partial = (float*)alloc((size_t)nposts * 16 * 4);

    (void)hipMemsetAsync(out, 0, (size_t)out_size * 4, stream);
    (void)hipMemsetAsync(cnt, 0, 16 * CSTRIDE * 4, stream);
    (void)hipMemsetAsync(lcnt, 0, NE * CSTRIDE * 4, stream);

    int nrb = (T + 3) / 4;
    k_init<<<CVTB + nrb, 256, 0, stream>>>(W1, W1b, NE * HID * DIM,
                                           W2, W2b, NE * DIM * HID,
                                           x, Wr, xb, probs, tidx, tw, T);
    k_hist<<<64, 256, 0, stream>>>(tidx, cnt, T);
    k_post<<<nposts, 256, 0, stream>>>(tidx, tw, cnt, probs, lcnt, ltok, lwb,
                                       partial, T, cap, capM);
    k_tail<<<1, 64, 0, stream>>>(lcnt, loff, partial, out + (size_t)T * DIM, nposts, T);

    k_fc1<<<NE * mtmax * (HID / 128), 256, 0, stream>>>(
        xb, W1b, b1, lcnt, loff, ltok, hbuf, capM);
    k_fc2<<<NE * mtmax * (DIM / 128), 256, 0, stream>>>(
        hbuf, W2b, b2, lcnt, loff, ltok, lwb, out, capM);
}

// Round 15
// 255.900 us; speedup vs baseline: 1.7020x; 1.7020x over previous
//
#include <hip/hip_runtime.h>
#include <hip/hip_bf16.h>
#include <math.h>

#define DIM 512
#define HID 2048
#define NE  8
#define CSTRIDE 32   // counter padding: 128B apart
#define CVTB 1024    // blocks of k_init doing weight conversion

typedef __attribute__((ext_vector_type(8))) short short8;
typedef __attribute__((ext_vector_type(4))) float f32x4;
typedef unsigned short ushort_t;

static __device__ __forceinline__ ushort_t f2bf(float f) {
    unsigned int x = __builtin_bit_cast(unsigned int, f);
    unsigned int lsb = (x >> 16) & 1u;
    x += 0x7fffu + lsb;
    return (ushort_t)(x >> 16);
}
static __device__ __forceinline__ float bf2f(ushort_t u) {
    unsigned int x = ((unsigned int)u) << 16;
    return __builtin_bit_cast(float, x);
}

// tanh-form gelu in sigmoid form: ~8 VALU ops, no LDS (r10's LUT caused 7.8M
// bank conflicts). |err vs erf-gelu| <= ~1e-3 in h -> ~3e-4 in y, << 2e-2.
static __device__ __forceinline__ float fast_gelu(float v) {
    float z = v * fmaf(0.071354816f, v * v, 1.5957691f);
    return v * __builtin_amdgcn_rcpf(1.f + __expf(-z));
}

// async global->LDS, 16B per lane. LDS dest must be the WAVE-UNIFORM base.
static __device__ __forceinline__ void gld16(const void* g, void* l) {
    __builtin_amdgcn_global_load_lds(
        (const __attribute__((address_space(1))) void*)g,
        (__attribute__((address_space(3))) void*)l,
        16, 0, 0);
}

// ---------------- fused init: weight cvt (blocks 0..CVTB) + router (rest) ----------------
__global__ __launch_bounds__(256) void k_init(
    const float* __restrict__ W1, ushort_t* __restrict__ W1b, int n1,
    const float* __restrict__ W2, ushort_t* __restrict__ W2b, int n2,
    const float* __restrict__ x, const float* __restrict__ Wr,
    ushort_t* __restrict__ xb, float* __restrict__ probs,
    int* __restrict__ tidx, float* __restrict__ tw, int T)
{
    if (blockIdx.x < CVTB) {
        int i = blockIdx.x * 256 + threadIdx.x;
        int stride = CVTB * 256;
        int n4a = n1 >> 2, n4b = n2 >> 2;
        for (int j = i; j < n4a; j += stride) {
            float4 v = ((const float4*)W1)[j];
            ushort4 o;
            o.x = f2bf(v.x); o.y = f2bf(v.y); o.z = f2bf(v.z); o.w = f2bf(v.w);
            ((ushort4*)W1b)[j] = o;
        }
        for (int j = i; j < n4b; j += stride) {
            float4 v = ((const float4*)W2)[j];
            ushort4 o;
            o.x = f2bf(v.x); o.y = f2bf(v.y); o.z = f2bf(v.z); o.w = f2bf(v.w);
            ((ushort4*)W2b)[j] = o;
        }
        return;
    }
    int lane = threadIdx.x & 63;
    int t = (blockIdx.x - CVTB) * 4 + (threadIdx.x >> 6);
    if (t >= T) return;
    const float* xr = x + (size_t)t * DIM;
    double acc[NE];
#pragma unroll
    for (int e = 0; e < NE; e++) acc[e] = 0.0;
    for (int i = lane; i < DIM; i += 64) {
        float xv = xr[i];
        xb[(size_t)t * DIM + i] = f2bf(xv);
        double xd = (double)xv;
#pragma unroll
        for (int e = 0; e < NE; e++) acc[e] += xd * (double)Wr[e * DIM + i];
    }
#pragma unroll
    for (int e = 0; e < NE; e++) {
#pragma unroll
        for (int off = 32; off > 0; off >>= 1) acc[e] += __shfl_xor(acc[e], off);
    }
    double mx = acc[0];
#pragma unroll
    for (int e = 1; e < NE; e++) mx = fmax(mx, acc[e]);
    double p[NE], sum = 0.0;
#pragma unroll
    for (int e = 0; e < NE; e++) { p[e] = exp(acc[e] - mx); sum += p[e]; }
    float pr[NE];
#pragma unroll
    for (int e = 0; e < NE; e++) pr[e] = (float)(p[e] / sum);
    if (lane < NE) probs[(size_t)t * NE + lane] = pr[lane];
    if (lane == 0) {
        int i1 = 0; float b1v = pr[0];
#pragma unroll
        for (int e = 1; e < NE; e++) if (pr[e] > b1v) { b1v = pr[e]; i1 = e; }
        int i2 = -1; float b2v = -1.f;
#pragma unroll
        for (int e = 0; e < NE; e++) if (e != i1 && pr[e] > b2v) { b2v = pr[e]; i2 = e; }
        float s2 = b1v + b2v + 1e-8f;
        tidx[t * 2] = i1; tidx[t * 2 + 1] = i2;
        tw[t * 2] = b1v / s2; tw[t * 2 + 1] = b2v / s2;
    }
}

// ---------------- per-(slot,expert) histogram: block-aggregated ----------------
__global__ __launch_bounds__(256) void k_hist(const int* __restrict__ tidx,
                                              int* __restrict__ cnt, int T) {
    __shared__ int h[16];
    if (threadIdx.x < 16) h[threadIdx.x] = 0;
    __syncthreads();
    int stride = gridDim.x * blockDim.x;
    for (int t = blockIdx.x * blockDim.x + threadIdx.x; t < T; t += stride) {
        atomicAdd(&h[tidx[t * 2]], 1);
        atomicAdd(&h[8 + tidx[t * 2 + 1]], 1);
    }
    __syncthreads();
    if (threadIdx.x < 16 && h[threadIdx.x] != 0)
        atomicAdd(&cnt[threadIdx.x * CSTRIDE], h[threadIdx.x]);
}

// ---------------- fused: capacity keep + renorm + merged build + aux partials ----------------
__global__ __launch_bounds__(256) void k_post(const int* __restrict__ tidx,
        const float* __restrict__ tw, const int* __restrict__ cnt,
        const float* __restrict__ probs, int* __restrict__ lcnt,
        int* __restrict__ ltok, int* __restrict__ pos, float* __restrict__ tw2,
        float* __restrict__ partial, int T, int cap, int capM)
{
    __shared__ int h[NE];
    __shared__ int base[NE];
    __shared__ float red[256 * 16];
    if (threadIdx.x < NE) h[threadIdx.x] = 0;
    __syncthreads();
    int t = blockIdx.x * blockDim.x + threadIdx.x;
    float wkn[2] = {0.f, 0.f};
    int myE[2] = {-1, -1};
    int myp[2] = {0, 0};
    if (t < T) {
        float wk[2]; int es[2];
#pragma unroll
        for (int s = 0; s < 2; s++) {
            int e = tidx[t * 2 + s];
            float w = tw[t * 2 + s];
            es[s] = e; wk[s] = w;
            if (cnt[(s * NE + e) * CSTRIDE] > cap) {   // rare: exact stable-sort rank
                int rank = 0;
                for (int t2 = 0; t2 < T; t2++) {
                    if (tidx[t2 * 2 + s] == e) {
                        float w2 = tw[t2 * 2 + s];
                        if (w2 > w || (w2 == w && t2 < t)) rank++;
                    }
                }
                if (rank >= cap) wk[s] = 0.f;
            }
        }
        float denom = fmaxf(wk[0] + wk[1], 1e-8f);
#pragma unroll
        for (int s = 0; s < 2; s++) {
            wkn[s] = wk[s] / denom;
            tw2[t * 2 + s] = wkn[s];
            if (wkn[s] != 0.f) {
                myE[s] = es[s];
                myp[s] = atomicAdd(&h[es[s]], 1);   // LDS atomic
            }
        }
    }
    __syncthreads();
    if (threadIdx.x < NE)
        base[threadIdx.x] = (h[threadIdx.x] != 0)
            ? atomicAdd(&lcnt[threadIdx.x * CSTRIDE], h[threadIdx.x]) : 0;
    __syncthreads();
    float imp[NE], ld[NE];
#pragma unroll
    for (int e = 0; e < NE; e++) { imp[e] = 0.f; ld[e] = 0.f; }
    if (t < T) {
#pragma unroll
        for (int s = 0; s < 2; s++) {
            if (myE[s] >= 0) {
                int p = base[myE[s]] + myp[s];
                ltok[myE[s] * capM + p] = t;
                pos[t * 2 + s] = (myE[s] << 20) | p;
                ld[myE[s]] += wkn[s];
            } else {
                pos[t * 2 + s] = -1;
            }
        }
#pragma unroll
        for (int e = 0; e < NE; e++) imp[e] = probs[(size_t)t * NE + e];
    }
#pragma unroll
    for (int e = 0; e < NE; e++) {
        red[threadIdx.x * 16 + e] = imp[e];
        red[threadIdx.x * 16 + 8 + e] = ld[e];
    }
    __syncthreads();
    for (int off = 128; off > 0; off >>= 1) {
        if (threadIdx.x < off) {
#pragma unroll
            for (int j = 0; j < 16; j++)
                red[threadIdx.x * 16 + j] += red[(threadIdx.x + off) * 16 + j];
        }
        __syncthreads();
    }
    if (threadIdx.x < 16) partial[blockIdx.x * 16 + threadIdx.x] = red[threadIdx.x];
}

// ---------------- tail: 128-aligned prefix offsets + aux final ----------------
__global__ void k_tail(const int* __restrict__ lcnt, int* __restrict__ loff,
                       const float* __restrict__ partial, float* __restrict__ outaux,
                       int nb, int T)
{
    __shared__ float s[16];
    if (threadIdx.x == 0) {
        int o = 0;
        for (int e = 0; e < NE; e++) {
            loff[e] = o;
            o += ((lcnt[e * CSTRIDE] + 127) >> 7) << 7;   // 128-row aligned tiles
        }
        loff[NE] = o;
    }
    if (threadIdx.x < 16) {
        float a = 0.f;
        for (int b = 0; b < nb; b++) a += partial[b * 16 + threadIdx.x];
        s[threadIdx.x] = a;
    }
    __syncthreads();
    if (threadIdx.x == 0) {
        float invT = 1.f / (float)T;
        float aux = 0.f;
        for (int e = 0; e < NE; e++)
            aux += (s[e] * invT) * (s[8 + e] * invT) * (float)NE;
        outaux[0] = aux;
    }
}

// ---------------- fc1: h = gelu(X @ W1^T + b1), 128x128, dbuf + counted vmcnt ----------------
// Pipeline (r9/r11-proven): STAGE(t+1) -> s_waitcnt vmcnt(8) -> raw s_barrier
// -> COMPUTE -> s_barrier. acc initialized with BIAS (C-in carries it through).
__global__ __launch_bounds__(256, 2) void k_fc1(
    const ushort_t* __restrict__ xb, const ushort_t* __restrict__ W1b,
    const float* __restrict__ b1, const int* __restrict__ lcnt,
    const int* __restrict__ loff, const int* __restrict__ ltok,
    ushort_t* __restrict__ hbuf, int capM)
{
    int bx = blockIdx.x;
    int e  = bx & 7;                 // expert == XCD residue
    int r  = bx >> 3;
    int mt = r >> 4;                 // HID/128 = 16 n-tiles, nt fastest
    int nt = r & 15;
    int cnt = lcnt[e * CSTRIDE];
    if (cnt > capM) cnt = capM;
    int m0 = mt * 128;
    if (m0 >= cnt) return;
    int n0 = nt * 128;
    const int* toks = ltok + e * capM;
    int hrow0 = loff[e] + m0;
    const ushort_t* Bsrc = W1b + (size_t)e * HID * DIM;

    __shared__ char smem[65536];     // dbuf: 2 x (16K A + 16K B)
    char* As0 = smem;          char* Bs0 = smem + 16384;
    char* As1 = smem + 32768;  char* Bs1 = smem + 49152;

    int tid = threadIdx.x;
    int wave = tid >> 6, lane = tid & 63;
    int wm = wave >> 1, wn = wave & 1;

    const char* aSrc[4]; const char* bSrc[4]; int ldst[4];
#pragma unroll
    for (int i = 0; i < 4; i++) {
        int c = tid + 256 * i;
        int row = c >> 3, cc = c & 7;
        int scc = cc ^ (row & 7);          // pre-swizzled source column chunk
        int gr = m0 + row;
        int tok = toks[gr < cnt ? gr : (cnt - 1)];
        aSrc[i] = (const char*)(xb + (size_t)tok * DIM + scc * 8);
        bSrc[i] = (const char*)(Bsrc + (size_t)(n0 + row) * DIM + scc * 8);
        ldst[i] = (i * 256 + wave * 64) * 16;
    }

    // acc init = bias (same per-column bias for every mf row-block)
    const float* b1e = b1 + e * HID;
    int nbase0 = n0 + wn * 64 + (lane >> 4) * 4;
    f32x4 acc[4][4];
#pragma unroll
    for (int nf = 0; nf < 4; nf++) {
        float4 bias4 = *(const float4*)(b1e + nbase0 + nf * 16);
        f32x4 bi = (f32x4){bias4.x, bias4.y, bias4.z, bias4.w};
#pragma unroll
        for (int mf = 0; mf < 4; mf++) acc[mf][nf] = bi;
    }

    int aRow = wm * 64 + (lane & 15);
    int bRow = wn * 64 + (lane & 15);
    int kq = lane >> 4;
    int swz0 = (kq ^ (lane & 7)) << 4;
    int swz1 = ((4 + kq) ^ (lane & 7)) << 4;
    int aoff[2] = { aRow * 128 + swz0, aRow * 128 + swz1 };
    int boff[2] = { bRow * 128 + swz0, bRow * 128 + swz1 };

    auto STAGE = [&](int kofs, char* A, char* B) {
#pragma unroll
        for (int i = 0; i < 4; i++) {
            gld16(aSrc[i] + kofs, A + ldst[i]);
            gld16(bSrc[i] + kofs, B + ldst[i]);
        }
    };
    auto COMPUTE = [&](const char* A, const char* B) {
#pragma unroll
        for (int kk = 0; kk < 2; kk++) {
            short8 af[4], bfr[4];
#pragma unroll
            for (int mf = 0; mf < 4; mf++)
                af[mf] = *(const short8*)(A + aoff[kk] + mf * 2048);
#pragma unroll
            for (int nf = 0; nf < 4; nf++)
                bfr[nf] = *(const short8*)(B + boff[kk] + nf * 2048);
#pragma unroll
            for (int mf = 0; mf < 4; mf++)
#pragma unroll
                for (int nf = 0; nf < 4; nf++)
                    acc[mf][nf] = __builtin_amdgcn_mfma_f32_16x16x32_bf16(bfr[nf], af[mf], acc[mf][nf], 0, 0, 0);
        }
    };

    const int NT = DIM / 64;   // 8
    STAGE(0, As0, Bs0);
#pragma unroll
    for (int t = 0; t < NT; t++) {
        char* Ac = (t & 1) ? As1 : As0;
        char* Bc = (t & 1) ? Bs1 : Bs0;
        if (t + 1 < NT) {
            STAGE((t + 1) * 128, (t & 1) ? As0 : As1, (t & 1) ? Bs0 : Bs1);
            asm volatile("s_waitcnt vmcnt(8)" ::: "memory");   // tile t done; t+1 in flight
        } else {
            asm volatile("s_waitcnt vmcnt(0)" ::: "memory");
        }
        __builtin_amdgcn_s_barrier();
        __builtin_amdgcn_sched_barrier(0);
        COMPUTE(Ac, Bc);
        __builtin_amdgcn_sched_barrier(0);
        __builtin_amdgcn_s_barrier();                          // buffer free for t+2
    }

    int mlocal = wm * 64 + (lane & 15);
#pragma unroll
    for (int mf = 0; mf < 4; mf++) {
        int mrow = mlocal + mf * 16;
        bool valid = (m0 + mrow) < cnt;
        ushort_t* dst = hbuf + (size_t)(hrow0 + mrow) * HID;
#pragma unroll
        for (int nf = 0; nf < 4; nf++) {
            int nc = nbase0 + nf * 16;
            ushort4 o;
            o.x = f2bf(fast_gelu(acc[mf][nf][0]));
            o.y = f2bf(fast_gelu(acc[mf][nf][1]));
            o.z = f2bf(fast_gelu(acc[mf][nf][2]));
            o.w = f2bf(fast_gelu(acc[mf][nf][3]));
            if (valid) *(ushort4*)(dst + nc) = o;
        }
    }
}

// ---------------- fc2: ybuf[row] = H @ W2^T + b2, same pipelined structure ----------------
__global__ __launch_bounds__(256, 2) void k_fc2(
    const ushort_t* __restrict__ hbuf, const ushort_t* __restrict__ W2b,
    const float* __restrict__ b2, const int* __restrict__ lcnt,
    const int* __restrict__ loff, ushort_t* __restrict__ ybuf, int capM)
{
    int bx = blockIdx.x;
    int e  = bx & 7;
    int r  = bx >> 3;
    int mt = r >> 2;                 // DIM/128 = 4 n-tiles
    int nt = r & 3;
    int cnt = lcnt[e * CSTRIDE];
    if (cnt > capM) cnt = capM;
    int m0 = mt * 128;
    if (m0 >= cnt) return;
    int n0 = nt * 128;
    int hrow0 = loff[e] + m0;
    const ushort_t* Bsrc = W2b + (size_t)e * DIM * HID;

    __shared__ char smem[65536];
    char* As0 = smem;          char* Bs0 = smem + 16384;
    char* As1 = smem + 32768;  char* Bs1 = smem + 49152;

    int tid = threadIdx.x;
    int wave = tid >> 6, lane = tid & 63;
    int wm = wave >> 1, wn = wave & 1;

    const char* aSrc[4]; const char* bSrc[4]; int ldst[4];
#pragma unroll
    for (int i = 0; i < 4; i++) {
        int c = tid + 256 * i;
        int row = c >> 3, cc = c & 7;
        int scc = cc ^ (row & 7);
        aSrc[i] = (const char*)(hbuf + (size_t)(hrow0 + row) * HID + scc * 8);
        bSrc[i] = (const char*)(Bsrc + (size_t)(n0 + row) * HID + scc * 8);
        ldst[i] = (i * 256 + wave * 64) * 16;
    }

    const float* b2e = b2 + e * DIM;
    int nbase0 = n0 + wn * 64 + (lane >> 4) * 4;
    f32x4 acc[4][4];
#pragma unroll
    for (int nf = 0; nf < 4; nf++) {
        float4 bias4 = *(const float4*)(b2e + nbase0 + nf * 16);
        f32x4 bi = (f32x4){bias4.x, bias4.y, bias4.z, bias4.w};
#pragma unroll
        for (int mf = 0; mf < 4; mf++) acc[mf][nf] = bi;
    }

    int aRow = wm * 64 + (lane & 15);
    int bRow = wn * 64 + (lane & 15);
    int kq = lane >> 4;
    int swz0 = (kq ^ (lane & 7)) << 4;
    int swz1 = ((4 + kq) ^ (lane & 7)) << 4;
    int aoff[2] = { aRow * 128 + swz0, aRow * 128 + swz1 };
    int boff[2] = { bRow * 128 + swz0, bRow * 128 + swz1 };

    auto STAGE = [&](int kofs, char* A, char* B) {
#pragma unroll
        for (int i = 0; i < 4; i++) {
            gld16(aSrc[i] + kofs, A + ldst[i]);
            gld16(bSrc[i] + kofs, B + ldst[i]);
        }
    };
    auto COMPUTE = [&](const char* A, const char* B) {
#pragma unroll
        for (int kk = 0; kk < 2; kk++) {
            short8 af[4], bfr[4];
#pragma unroll
            for (int mf = 0; mf < 4; mf++)
                af[mf] = *(const short8*)(A + aoff[kk] + mf * 2048);
#pragma unroll
            for (int nf = 0; nf < 4; nf++)
                bfr[nf] = *(const short8*)(B + boff[kk] + nf * 2048);
#pragma unroll
            for (int mf = 0; mf < 4; mf++)
#pragma unroll
                for (int nf = 0; nf < 4; nf++)
                    acc[mf][nf] = __builtin_amdgcn_mfma_f32_16x16x32_bf16(bfr[nf], af[mf], acc[mf][nf], 0, 0, 0);
        }
    };

    const int NT = HID / 64;   // 32 (byte offsets 0..3968 fit 13-bit signed imm)
    STAGE(0, As0, Bs0);
#pragma unroll
    for (int t = 0; t < NT; t++) {
        char* Ac = (t & 1) ? As1 : As0;
        char* Bc = (t & 1) ? Bs1 : Bs0;
        if (t + 1 < NT) {
            STAGE((t + 1) * 128, (t & 1) ? As0 : As1, (t & 1) ? Bs0 : Bs1);
            asm volatile("s_waitcnt vmcnt(8)" ::: "memory");
        } else {
            asm volatile("s_waitcnt vmcnt(0)" ::: "memory");
        }
        __builtin_amdgcn_s_barrier();
        __builtin_amdgcn_sched_barrier(0);
        COMPUTE(Ac, Bc);
        __builtin_amdgcn_sched_barrier(0);
        __builtin_amdgcn_s_barrier();
    }

    int mlocal = wm * 64 + (lane & 15);
#pragma unroll
    for (int mf = 0; mf < 4; mf++) {
        int mrow = mlocal + mf * 16;
        bool valid = (m0 + mrow) < cnt;
        ushort_t* dst = ybuf + (size_t)(hrow0 + mrow) * DIM;
#pragma unroll
        for (int nf = 0; nf < 4; nf++) {
            int nc = nbase0 + nf * 16;
            ushort4 o;
            o.x = f2bf(acc[mf][nf][0]);
            o.y = f2bf(acc[mf][nf][1]);
            o.z = f2bf(acc[mf][nf][2]);
            o.w = f2bf(acc[mf][nf][3]);
            if (valid) *(ushort4*)(dst + nc) = o;
        }
    }
}

// ---------------- combine: out[t] = w0*ybuf[row0] + w1*ybuf[row1] ----------------
__global__ __launch_bounds__(256) void k_comb(const ushort_t* __restrict__ ybuf,
    const float* __restrict__ tw2, const int* __restrict__ pos,
    const int* __restrict__ loff, float* __restrict__ out, int T, int capM)
{
    int wv = threadIdx.x >> 6, lane = threadIdx.x & 63;
#pragma unroll
    for (int half = 0; half < 2; half++) {
        int t = blockIdx.x * 8 + wv * 2 + half;
        if (t >= T) continue;
        float o[8];
#pragma unroll
        for (int j = 0; j < 8; j++) o[j] = 0.f;
#pragma unroll
        for (int s = 0; s < 2; s++) {
            int pk = pos[t * 2 + s];
            if (pk >= 0) {
                float w = tw2[t * 2 + s];
                int e = pk >> 20, p = pk & 0xFFFFF;
                int row = loff[e] + p;
                short8 y = *(const short8*)(ybuf + (size_t)row * DIM + lane * 8);
#pragma unroll
                for (int j = 0; j < 8; j++) o[j] += w * bf2f((ushort_t)y[j]);
            }
        }
        float4* dst = (float4*)(out + (size_t)t * DIM + lane * 8);
        dst[0] = (float4){o[0], o[1], o[2], o[3]};
        dst[1] = (float4){o[4], o[5], o[6], o[7]};
    }
}

// ---------------- launch ----------------
extern "C" void kernel_launch(void* const* d_in, const int* in_sizes, int n_in,
                              void* d_out, int out_size, void* d_ws, size_t ws_size,
                              hipStream_t stream)
{
    const float* x  = (const float*)d_in[0];
    const float* Wr = (const float*)d_in[1];
    const float* W1 = (const float*)d_in[2];
    const float* b1 = (const float*)d_in[3];
    const float* W2 = (const float*)d_in[4];
    const float* b2 = (const float*)d_in[5];
    float* out = (float*)d_out;

    int T = in_sizes[0] / DIM;
    int cap = (int)(1.25 * (double)T * 2.0 / 8.0);
    if (cap < 1) cap = 1;
    int capM = 2 * cap; if (capM > T) capM = T;      // merged per-expert bound
    int mtmax = (capM + 127) / 128;                   // 128-row m-tiles
    int nposts = (T + 255) / 256;

    char* w = (char*)d_ws;
    size_t off = 0;
    auto alloc = [&](size_t bytes) {
        char* p = w + off;
        off = (off + bytes + 255) & ~(size_t)255;
        return p;
    };
    // ybuf overlays xb+W1b (both dead before fc2 writes ybuf)
    size_t ybrows = (size_t)T * 2 + NE * 128;
    size_t ybbytes = ybrows * DIM * 2;
    ushort_t* ybuf = (ushort_t*)w;                    // offset 0
    ushort_t* xb   = (ushort_t*)alloc((size_t)T * DIM * 2);
    ushort_t* W1b  = (ushort_t*)alloc((size_t)NE * HID * DIM * 2);
    if (off < ybbytes) off = (ybbytes + 255) & ~(size_t)255;
    ushort_t* W2b  = (ushort_t*)alloc((size_t)NE * DIM * HID * 2);
    ushort_t* hbuf = (ushort_t*)alloc(ybrows * HID * 2);
    float* probs   = (float*)alloc((size_t)T * NE * 4);
    int*   tidx    = (int*)alloc((size_t)T * 2 * 4);
    float* tw      = (float*)alloc((size_t)T * 2 * 4);
    float* tw2     = (float*)alloc((size_t)T * 2 * 4);
    int*   pos     = (int*)alloc((size_t)T * 2 * 4);
    int*   cnt     = (int*)alloc(16 * CSTRIDE * 4);
    int*   lcnt    = (int*)alloc(NE * CSTRIDE * 4);
    int*   loff    = (int*)alloc((NE + 1) * 4);
    int*   ltok    = (int*)alloc((size_t)NE * capM * 4);
    float* partial = (float*)alloc((size_t)nposts * 16 * 4);

    (void)hipMemsetAsync(cnt, 0, 16 * CSTRIDE * 4, stream);
    (void)hipMemsetAsync(lcnt, 0, NE * CSTRIDE * 4, stream);

    int nrb = (T + 3) / 4;
    k_init<<<CVTB + nrb, 256, 0, stream>>>(W1, W1b, NE * HID * DIM,
                                           W2, W2b, NE * DIM * HID,
                                           x, Wr, xb, probs, tidx, tw, T);
    k_hist<<<64, 256, 0, stream>>>(tidx, cnt, T);
    k_post<<<nposts, 256, 0, stream>>>(tidx, tw, cnt, probs, lcnt, ltok, pos, tw2,
                                       partial, T, cap, capM);
    k_tail<<<1, 64, 0, stream>>>(lcnt, loff, partial, out + (size_t)T * DIM, nposts, T);

    k_fc1<<<NE * mtmax * (HID / 128), 256, 0, stream>>>(
        xb, W1b, b1, lcnt, loff, ltok, hbuf, capM);
    k_fc2<<<NE * mtmax * (DIM / 128), 256, 0, stream>>>(
        hbuf, W2b, b2, lcnt, loff, ybuf, capM);
    k_comb<<<(T + 7) / 8, 256, 0, stream>>>(ybuf, tw2, pos, loff, out, T, capM);
}